// Round 21
// baseline (252.426 us; speedup 1.0000x reference)
//
#include <hip/hip_runtime.h>
#include <hip/hip_bf16.h>

// r21 = r19 with norm_pool at 512 threads/block (8 waves, 32 ch/wave): raises
// waves/CU 16->24 at unchanged 128B read segments. Evidence r12-r20: all
// 256-thread variants plateau 106-118us latency-bound at 16 waves/CU; the only
// occupancy-raising variant (r13) regressed solely from halved read segments.

#define B_ 4
#define C_ 256
#define ND_ 81

typedef float  f32x4 __attribute__((ext_vector_type(4)));
typedef float  f32x2 __attribute__((ext_vector_type(2)));
typedef unsigned int u32x4 __attribute__((ext_vector_type(4)));
typedef __bf16 bf16x8 __attribute__((ext_vector_type(8)));
typedef unsigned short u16x4 __attribute__((ext_vector_type(4)));

__device__ __forceinline__ unsigned short f2bf(float f) {
  unsigned int u = __builtin_bit_cast(unsigned int, f);
  u += 0x7FFFu + ((u >> 16) & 1u);   // RNE
  return (unsigned short)(u >> 16);
}

__device__ __forceinline__ void gload16(const void* g, void* l) {
  __builtin_amdgcn_global_load_lds(
      (const __attribute__((address_space(1))) unsigned int*)g,
      (__attribute__((address_space(3))) unsigned int*)l, 16, 0, 0);
}

// ------- fused: normalize+transpose (padded dst2) + 2x2 pool, lane-local -------
// block = 2x32 px tile, 512 threads (8 waves x 32 channels); lane=(cg,pq).
// Thread owns the 2x2 quad of 8 channels (2 groups of 4 contiguous).
template<int W>
__global__ __launch_bounds__(512) void norm_pool(
    const float* __restrict__ src1, const float* __restrict__ src2,
    unsigned short* __restrict__ dst1, unsigned short* __restrict__ dst2,
    float* __restrict__ pool1, float* __restrict__ pool2) {
  constexpr int HW = W * W, Wp = W + 8, W1 = W / 2, HW1 = W1 * W1;
  constexpr bool FULLX = (W % 32 == 0);
  __shared__ unsigned short raw[64 * 260];
  __shared__ float ssl[512][4];
  __shared__ float inv[64];
  int tid = threadIdx.x;
  int lane = tid & 63, w = tid >> 6;        // w in [0,8)
  int cg = lane >> 4, pq = lane & 15;
  int x0 = blockIdx.x * 32, y0 = blockIdx.y * 2;
  int z = blockIdx.z, b = z >> 1;
  bool pad = (z & 1) != 0;
  const float* src = pad ? src2 : src1;
  unsigned short* dst = pad ? dst2 : dst1;
  float* pooled = pad ? pool2 : pool1;
  bool okc = FULLX || ((x0 + 2 * pq) < W);
  const float* base0 = src + (long)b * C_ * HW + (long)y0 * W + x0 + 2 * pq;
  long pbase = (long)b * C_ * HW1 + (long)(y0 >> 1) * W1 + (x0 >> 1) + pq;
  int p00 = 2 * pq, p10 = 32 + 2 * pq;

  float ss0 = 0.f, ss1 = 0.f, ss2 = 0.f, ss3 = 0.f;
  f32x2 va[8][2];
  // one 16-deep load batch: 8 channels x 2 rows
#pragma unroll
  for (int h = 0; h < 8; ++h) {
    int c = w * 32 + (h >> 2) * 16 + cg * 4 + (h & 3);
    f32x2 z2 = {0.f, 0.f};
    va[h][0] = z2; va[h][1] = z2;
    if (okc) {
      va[h][0] = *(const f32x2*)(base0 + (long)c * HW);
      va[h][1] = *(const f32x2*)(base0 + (long)c * HW + W);
    }
  }
#pragma unroll
  for (int g = 0; g < 2; ++g) {
    int c0 = w * 32 + g * 16 + cg * 4;
    u16x4 pk00, pk01, pk10, pk11;
#pragma unroll
    for (int j = 0; j < 4; ++j) {
      int h = g * 4 + j;
      float v00 = va[h][0].x, v01 = va[h][0].y;
      float v10 = va[h][1].x, v11 = va[h][1].y;
      ss0 += v00 * v00; ss1 += v01 * v01;
      ss2 += v10 * v10; ss3 += v11 * v11;
      pk00[j] = f2bf(v00); pk01[j] = f2bf(v01);
      pk10[j] = f2bf(v10); pk11[j] = f2bf(v11);
      if (okc) pooled[pbase + (long)(c0 + j) * HW1] = 0.25f * ((v00 + v01) + (v10 + v11));
    }
    *(u16x4*)&raw[p00 * 260 + c0]       = pk00;   // ds_write_b64, ~2-way banks
    *(u16x4*)&raw[(p00 + 1) * 260 + c0] = pk01;
    *(u16x4*)&raw[p10 * 260 + c0]       = pk10;
    *(u16x4*)&raw[(p10 + 1) * 260 + c0] = pk11;
  }
  ssl[tid][0] = ss0; ssl[tid][1] = ss1; ssl[tid][2] = ss2; ssl[tid][3] = ss3;
  __syncthreads();
  if (tid < 64) {
    int r = tid >> 5, col = tid & 31;
    int pq2 = col >> 1, j = r * 2 + (col & 1);
    float s = 0.f;
#pragma unroll
    for (int ww = 0; ww < 8; ++ww)
#pragma unroll
      for (int g = 0; g < 4; ++g)
        s += ssl[ww * 64 + g * 16 + pq2][j];
    inv[tid] = 1.f / fmaxf(sqrtf(s), 1e-12f);
  }
  __syncthreads();

  int c4 = lane * 4;
  for (int p = w; p < 64; p += 8) {
    int y = y0 + (p >> 5), x = x0 + (p & 31);
    if (FULLX || x < W) {
      long off;
      if (pad) off = (((long)b * Wp + (y + 4)) * Wp + (x + 4)) * C_ + c4;
      else     off = ((long)b * HW + (long)y * W + x) * C_ + c4;
      u16x4 r = *(const u16x4*)&raw[p * 260 + c4];
      float sc = inv[p];
      u16x4 o;
#pragma unroll
      for (int j = 0; j < 4; ++j) {
        float v = __builtin_bit_cast(float, ((unsigned int)r[j]) << 16) * sc;
        o[j] = f2bf(v);
      }
      *(u16x4*)&dst[off] = o;
    }
  }
}

// ------- depth-only 2x2 pool -------
template<int Wi>
__global__ void pool_d(const float* __restrict__ d1i, const float* __restrict__ d2i,
                       float* __restrict__ d1o, float* __restrict__ d2o) {
  constexpr int Wo = Wi / 2, HWo = Wo * Wo, N = 2 * B_ * HWo;
  int i = blockIdx.x * 256 + threadIdx.x;
  if (i >= N) return;
  const float* src = (i < B_ * HWo) ? d1i : d2i;
  float* dst = (i < B_ * HWo) ? d1o : d2o;
  int r = (i < B_ * HWo) ? i : i - B_ * HWo;
  int pl = r / HWo, pix = r - pl * HWo;
  int yo = pix / Wo, xo = pix - yo * Wo;
  const float* p0 = src + ((long)pl * Wi + 2 * yo) * Wi + 2 * xo;
  f32x2 a = *(const f32x2*)p0;
  f32x2 c = *(const f32x2*)(p0 + Wi);
  dst[r] = 0.25f * (a.x + a.y + c.x + c.y);
}

// ------- 2x2 average pooling (fmaps+depth), level 2->3 (r10-proven) -------
template<int Ho, int Wo>
__global__ __launch_bounds__(256) void pool16(
    const float* __restrict__ f1i, const float* __restrict__ f2i,
    const float* __restrict__ d1i, const float* __restrict__ d2i,
    float* __restrict__ f1o, float* __restrict__ f2o,
    float* __restrict__ d1o, float* __restrict__ d2o) {
  constexpr long HWo = (long)Ho * Wo;
  constexpr long G4F = (long)B_ * C_ * HWo / 4;
  constexpr long G4D = (long)B_ * HWo / 4;
  constexpr long N   = 2 * G4F + 2 * G4D;
  constexpr long TT  = N / 4;
  long t = (long)blockIdx.x * blockDim.x + threadIdx.x;
  if (t >= TT) return;
  f32x4 va[4][4];
  float* dsts[4];
  long   gs[4];
#pragma unroll
  for (int j = 0; j < 4; ++j) {
    long g = t + (long)j * TT;
    const float* src; float* dst;
    if      (g < G4F)           { src = f1i; dst = f1o; }
    else if (g < 2*G4F)         { src = f2i; dst = f2o; g -= G4F; }
    else if (g < 2*G4F + G4D)   { src = d1i; dst = d1o; g -= 2*G4F; }
    else                        { src = d2i; dst = d2o; g -= 2*G4F + G4D; }
    constexpr long GP = HWo / 4;
    long plane = g / GP;
    long gp    = g - plane * GP;
    int  yo    = (int)(gp / (Wo / 4));
    int  xg    = (int)(gp - (long)yo * (Wo / 4));
    constexpr int Wi = 2 * Wo;
    const float* p0 = src + (plane * (2 * Ho) + 2 * yo) * (long)Wi + 8 * xg;
    va[j][0] = *(const f32x4*)p0;
    va[j][1] = *(const f32x4*)(p0 + 4);
    va[j][2] = *(const f32x4*)(p0 + Wi);
    va[j][3] = *(const f32x4*)(p0 + Wi + 4);
    dsts[j] = dst;
    gs[j]   = g;
  }
#pragma unroll
  for (int j = 0; j < 4; ++j) {
    f32x4 o;
    o.x = 0.25f * (va[j][0].x + va[j][0].y + va[j][2].x + va[j][2].y);
    o.y = 0.25f * (va[j][0].z + va[j][0].w + va[j][2].z + va[j][2].w);
    o.z = 0.25f * (va[j][1].x + va[j][1].y + va[j][3].x + va[j][3].y);
    o.w = 0.25f * (va[j][1].z + va[j][1].w + va[j][3].z + va[j][3].w);
    *(f32x4*)(dsts[j] + 4 * gs[j]) = o;
  }
}

// ------- r4-proven: normalize + transpose, both compact (L2/L3 path) -------
__global__ __launch_bounds__(256) void norm_tp_c(
    const float* __restrict__ src1, const float* __restrict__ src2,
    unsigned short* __restrict__ dst1, unsigned short* __restrict__ dst2, int HW_) {
  __shared__ unsigned short raw[64 * 260];
  __shared__ float ssp[4][64];
  __shared__ float inv[64];
  int tid = threadIdx.x;
  int lane = tid & 63, w = tid >> 6;
  long HW = HW_;
  long pix0 = (long)blockIdx.x * 64;
  int z = blockIdx.z, b = z >> 1;
  const float* src = (z & 1) ? src2 : src1;
  unsigned short* dst = (z & 1) ? dst2 : dst1;
  bool ok = (pix0 + lane) < HW;
  const float* base = src + (long)b * C_ * HW + pix0 + lane;

  float ss = 0.f;
  float vv[16];
  for (int cb = 0; cb < 64; cb += 16) {
    int c0 = w * 64 + cb;
#pragma unroll
    for (int j = 0; j < 16; ++j)
      vv[j] = ok ? base[(long)(c0 + j) * HW] : 0.f;
#pragma unroll
    for (int g = 0; g < 4; ++g) {
      u16x4 pk;
#pragma unroll
      for (int j = 0; j < 4; ++j) {
        float v = vv[g * 4 + j];
        ss += v * v;
        pk[j] = f2bf(v);
      }
      *(u16x4*)&raw[lane * 260 + c0 + g * 4] = pk;
    }
  }
  ssp[w][lane] = ss;
  __syncthreads();
  if (tid < 64) {
    float s = ssp[0][tid] + ssp[1][tid] + ssp[2][tid] + ssp[3][tid];
    inv[tid] = 1.f / fmaxf(sqrtf(s), 1e-12f);
  }
  __syncthreads();
  int c4 = lane * 4;
  unsigned short* dbase = dst + ((long)b * HW + pix0) * C_;
  for (int p = w; p < 64; p += 4) {
    if (pix0 + p < HW) {
      u16x4 r = *(const u16x4*)&raw[p * 260 + c4];
      float sc = inv[p];
      u16x4 o;
#pragma unroll
      for (int j = 0; j < 4; ++j) {
        float v = __builtin_bit_cast(float, ((unsigned int)r[j]) << 16) * sc;
        o[j] = f2bf(v);
      }
      *(u16x4*)&dbase[(long)p * C_ + c4] = o;
    }
  }
}

// ------- zero the 4px halo of a padded [b][y'][x'][c] bf16 buffer -------
template<int W>
__global__ void zero_halo(unsigned short* __restrict__ fp) {
  constexpr int Wp = W + 8;
  constexpr long UN = (long)B_ * Wp * Wp * 32;
  long u = (long)blockIdx.x * 256 + threadIdx.x;
  if (u >= UN) return;
  long px = u >> 5;
  long pp = px % ((long)Wp * Wp);
  int y = (int)(pp / Wp), x = (int)(pp - (long)(pp / Wp) * Wp);
  if (y < 4 || y >= Wp - 4 || x < 4 || x >= Wp - 4) {
    u16x4 z4 = {0, 0, 0, 0};
    *(u16x4*)&fp[u * 8] = z4;
  }
}

// ---------------- corr2: LDS-staged, K-chunked, XCD-swizzled (L0/L1) ----------------
template<int W>
__global__ __launch_bounds__(256, 3) void corr2(
    const unsigned short* __restrict__ f1n, const unsigned short* __restrict__ f2pd,
    const float* __restrict__ d1, const float* __restrict__ d2,
    const float* __restrict__ dwp, float* __restrict__ out) {
  constexpr int H = W, Wp = W + 8, Hp = H + 8;
  constexpr int GX = (W + 15) / 16, GY = H / 4;
  constexpr int NB = GX * GY * B_;
  constexpr int CPX = NB / 8;
  constexpr int BUFB = 18944;
  __shared__ char smem[2 * BUFB];
  unsigned short* sb = (unsigned short*)smem;

  int tid = threadIdx.x;
  int lane = tid & 63, wv = tid >> 6;
  int n16 = lane & 15, hi = lane >> 4;

  int f = blockIdx.x;
  int nf = (f & 7) * CPX + (f >> 3);
  int j = nf % GY;
  int rest = nf / GY;
  int i = rest % GX;
  int b = rest / GX;
  int x0 = i * 16, y0 = j * 4, y = y0 + wv;
  long HW = (long)W * H;

  int xm = x0 + n16;
  bool aok = xm < W;
  const unsigned short* abase = f1n + ((long)b * HW + (long)y * W + xm) * C_ + hi * 8;
  bf16x8 afr[8];
#pragma unroll
  for (int kc = 0; kc < 8; ++kc) {
    u32x4 rr = {0u, 0u, 0u, 0u};
    if (aok) rr = *(const u32x4*)(abase + kc * 32);
    afr[kc] = __builtin_bit_cast(bf16x8, rr);
  }

  const char* gbase = (const char*)f2pd;
  long gb[5];
#pragma unroll
  for (int it = 0; it < 5; ++it) {
    int u = tid + it * 256;
    int u2 = (u < 1152) ? u : 0;
    int sl = (u2 & ~7) | ((u2 & 7) ^ ((u2 >> 3) & 7));
    int px = sl >> 2, s = sl & 3;
    int row = px / 24, col = px - row * 24;
    int gx = x0 + col; if (gx > Wp - 1) gx = Wp - 1;
    int gy = y0 + row;
    gb[it] = (((long)b * Hp + gy) * Wp + gx) * 512 + s * 16;
  }

  f32x4 acc[9][2];
#pragma unroll
  for (int dy = 0; dy < 9; ++dy)
#pragma unroll
    for (int nt = 0; nt < 2; ++nt)
      acc[dy][nt] = f32x4{0.f, 0.f, 0.f, 0.f};

#pragma unroll
  for (int it = 0; it < 5; ++it)
    if (tid + it * 256 < 1152)
      gload16(gbase + gb[it], smem + (tid + it * 256) * 16);
  __syncthreads();

#pragma unroll
  for (int kc = 0; kc < 8; ++kc) {
    int cur = kc & 1;
    if (kc < 7) {
      char* dstb = smem + (cur ^ 1) * BUFB;
#pragma unroll
      for (int it = 0; it < 5; ++it)
        if (tid + it * 256 < 1152)
          gload16(gbase + gb[it] + (long)(kc + 1) * 64, dstb + (tid + it * 256) * 16);
    }
    const unsigned short* bufc = sb + cur * (BUFB / 2);
#pragma unroll
    for (int dy = 0; dy < 9; ++dy) {
      int rbase = (wv + dy) * 96;
#pragma unroll
      for (int nt = 0; nt < 2; ++nt) {
        int sl = rbase + (nt * 16 + n16) * 4 + hi;
        int ph = (sl & ~7) | ((sl & 7) ^ ((sl >> 3) & 7));
        bf16x8 bfr = *(const bf16x8*)(bufc + ph * 8);
        acc[dy][nt] = __builtin_amdgcn_mfma_f32_16x16x32_bf16(afr[kc], bfr, acc[dy][nt], 0, 0, 0);
      }
    }
    __syncthreads();
  }

  float* lds_o = (float*)smem;
  float* dt = (float*)(smem + 64 * ND_ * 4);
#pragma unroll
  for (int dy = 0; dy < 9; ++dy)
#pragma unroll
    for (int nt = 0; nt < 2; ++nt)
#pragma unroll
      for (int r = 0; r < 4; ++r) {
        int m = hi * 4 + r;
        int dx = nt * 16 + n16 - m - 4;
        if (dx >= -4 && dx <= 4) {
          int d = (8 - dy) * 9 + (4 - dx);
          lds_o[(wv * 16 + m) * ND_ + d] = acc[dy][nt][r];
        }
      }
  if (tid < 64) {
    int ty = tid >> 4, tx = tid & 15;
    int xq = x0 + tx, yq = y0 + ty;
    float v = 0.f;
    if (xq < W) {
      long pidx = (long)b * HW + (long)yq * W + xq;
      v = dwp[0] * expf(-fabsf(d1[pidx] - d2[pidx]));
    }
    dt[tid] = v;
  }
  __syncthreads();
  long obase = (long)b * ND_ * HW;
  for (int it = 0; it < 21; ++it) {
    int flat = it * 256 + tid;
    if (flat < 64 * ND_) {
      int d = flat >> 6;
      int p = flat & 63;
      int xq = x0 + (p & 15);
      if (xq < W)
        out[obase + (long)d * HW + (long)(y0 + (p >> 4)) * W + xq] = lds_o[p * ND_ + d] + dt[p];
    }
  }
}

// ---------------- r4-proven corr (global-B, compact buffers) — L2/L3 ----------------
__global__ __launch_bounds__(256, 2) void corr_g(
    const unsigned short* __restrict__ f1n, const unsigned short* __restrict__ f2n,
    const float* __restrict__ d1, const float* __restrict__ d2,
    const float* __restrict__ dwp, float* __restrict__ out, int H, int W) {
  __shared__ float lds_o[64 * ND_];
  __shared__ float dt[64];
  int tid = threadIdx.x;
  int lane = tid & 63, wv = tid >> 6;
  int x0 = blockIdx.x * 16, y0 = blockIdx.y * 4, b = blockIdx.z;
  int y = y0 + wv;
  int n16 = lane & 15, hi = lane >> 4;
  long HW = (long)H * W;

  int xm = x0 + n16;
  bool aok = xm < W;
  const unsigned short* abase = f1n + ((long)b * HW + (long)y * W + xm) * C_ + hi * 8;
  bf16x8 afr[8];
#pragma unroll
  for (int ch = 0; ch < 8; ++ch) {
    u32x4 rr = {0u, 0u, 0u, 0u};
    if (aok) rr = *(const u32x4*)(abase + ch * 32);
    afr[ch] = __builtin_bit_cast(bf16x8, rr);
  }

  f32x4 acc[9][2];
#pragma unroll
  for (int dy = 0; dy < 9; ++dy)
#pragma unroll
    for (int nt = 0; nt < 2; ++nt)
      acc[dy][nt] = f32x4{0.f, 0.f, 0.f, 0.f};

#pragma unroll
  for (int dy = 0; dy < 9; ++dy) {
    int yy = y + dy - 4;
    if (yy >= 0 && yy < H) {
      const unsigned short* brow = f2n + ((long)b * HW + (long)yy * W) * C_;
#pragma unroll
      for (int nt = 0; nt < 2; ++nt) {
        int wx = x0 - 4 + nt * 16 + n16;
        bool bok = (wx >= 0) && (wx < W);
        const unsigned short* bbase = brow + (long)wx * C_ + hi * 8;
        bf16x8 bfr[8];
#pragma unroll
        for (int ch = 0; ch < 8; ++ch) {
          u32x4 rr = {0u, 0u, 0u, 0u};
          if (bok) rr = *(const u32x4*)(bbase + ch * 32);
          bfr[ch] = __builtin_bit_cast(bf16x8, rr);
        }
#pragma unroll
        for (int ch = 0; ch < 8; ++ch)
          acc[dy][nt] = __builtin_amdgcn_mfma_f32_16x16x32_bf16(afr[ch], bfr[ch], acc[dy][nt], 0, 0, 0);
      }
    }
  }

#pragma unroll
  for (int dy = 0; dy < 9; ++dy)
#pragma unroll
    for (int nt = 0; nt < 2; ++nt)
#pragma unroll
      for (int r = 0; r < 4; ++r) {
        int m = hi * 4 + r;
        int dx = nt * 16 + n16 - m - 4;
        if (dx >= -4 && dx <= 4) {
          int d = (8 - dy) * 9 + (4 - dx);
          lds_o[(wv * 16 + m) * ND_ + d] = acc[dy][nt][r];
        }
      }
  if (tid < 64) {
    int ty = tid >> 4, tx = tid & 15;
    int xq = x0 + tx, yq = y0 + ty;
    float v = 0.f;
    if (xq < W) {
      long pidx = (long)b * HW + (long)yq * W + xq;
      v = dwp[0] * expf(-fabsf(d1[pidx] - d2[pidx]));
    }
    dt[tid] = v;
  }
  __syncthreads();
  long obase = (long)b * ND_ * HW;
  for (int it = 0; it < 21; ++it) {
    int flat = it * 256 + tid;
    if (flat < 64 * ND_) {
      int d = flat >> 6;
      int p = flat & 63;
      int xq = x0 + (p & 15);
      if (xq < W)
        out[obase + (long)d * HW + (long)(y0 + (p >> 4)) * W + xq] = lds_o[p * ND_ + d] + dt[p];
    }
  }
}

// ---------------------------------------------------------------------------
extern "C" void kernel_launch(void* const* d_in, const int* in_sizes, int n_in,
                              void* d_out, int out_size, void* d_ws, size_t ws_size,
                              hipStream_t stream) {
  const float* f1  = (const float*)d_in[0];
  const float* f2  = (const float*)d_in[1];
  const float* dp1 = (const float*)d_in[2];
  const float* dp2 = (const float*)d_in[3];
  const float* dw  = (const float*)d_in[4];
  float* out = (float*)d_out;

  char* ws = (char*)d_ws;
  size_t off = 0;
  auto alloc = [&](size_t bytes) -> void* {
    void* p = ws + off;
    off = (off + bytes + 255) & ~(size_t)255;
    return p;
  };
  static const long HWs[4] = {25600, 6400, 1600, 400};
  float* f1p[4]; float* f2p[4]; float* d1p[4]; float* d2p[4];
  for (int l = 1; l <= 3; ++l) f1p[l] = (float*)alloc((size_t)B_ * C_ * HWs[l] * 4);
  for (int l = 1; l <= 3; ++l) f2p[l] = (float*)alloc((size_t)B_ * C_ * HWs[l] * 4);
  for (int l = 1; l <= 3; ++l) d1p[l] = (float*)alloc((size_t)B_ * HWs[l] * 4);
  for (int l = 1; l <= 3; ++l) d2p[l] = (float*)alloc((size_t)B_ * HWs[l] * 4);
  unsigned short* f1n0 = (unsigned short*)alloc((size_t)B_ * 25600 * C_ * 2);
  unsigned short* f1n1 = (unsigned short*)alloc((size_t)B_ * 6400 * C_ * 2);
  unsigned short* f2n0 = (unsigned short*)alloc((size_t)B_ * 168 * 168 * C_ * 2);
  unsigned short* f2n1 = (unsigned short*)alloc((size_t)B_ * 88 * 88 * C_ * 2);
  unsigned short* f1n2 = (unsigned short*)alloc((size_t)B_ * 1600 * C_ * 2);
  unsigned short* f2n2 = (unsigned short*)alloc((size_t)B_ * 1600 * C_ * 2);
  unsigned short* f1n3 = (unsigned short*)alloc((size_t)B_ * 400 * C_ * 2);
  unsigned short* f2n3 = (unsigned short*)alloc((size_t)B_ * 400 * C_ * 2);
  if (off > ws_size) return;

  // 1) fused L0: normalize + pool L0->L1 (fmaps); depth pools
  norm_pool<160><<<dim3(5, 80, 8), 512, 0, stream>>>(f1, f2, f1n0, f2n0, f1p[1], f2p[1]);
  pool_d<160><<<dim3(200), 256, 0, stream>>>(dp1, dp2, d1p[1], d2p[1]);

  // 2) fused L1: normalize + pool L1->L2 (fmaps); depth pool; L2->L3 pool
  norm_pool<80><<<dim3(3, 40, 8), 512, 0, stream>>>(f1p[1], f2p[1], f1n1, f2n1, f1p[2], f2p[2]);
  pool_d<80><<<dim3(50), 256, 0, stream>>>(d1p[1], d2p[1], d1p[2], d2p[2]);
  pool16<20, 20><<<dim3(201), 256, 0, stream>>>(
      f1p[2], f2p[2], d1p[2], d2p[2], f1p[3], f2p[3], d1p[3], d2p[3]);

  // 3) halo zero, then staged corr L0/L1
  zero_halo<160><<<dim3(14112), 256, 0, stream>>>(f2n0);
  zero_halo< 80><<<dim3( 3872), 256, 0, stream>>>(f2n1);
  corr2<160><<<dim3(1600), 256, 0, stream>>>(f1n0, f2n0, dp1,    dp2,    dw, out);
  corr2< 80><<<dim3( 400), 256, 0, stream>>>(f1n1, f2n1, d1p[1], d2p[1], dw, out + 8294400);

  // 4) L2/L3: r4-proven compact path (distinct buffers)
  norm_tp_c<<<dim3(25, 1, 8), 256, 0, stream>>>(f1p[2], f2p[2], f1n2, f2n2, 1600);
  norm_tp_c<<<dim3( 7, 1, 8), 256, 0, stream>>>(f1p[3], f2p[3], f1n3, f2n3, 400);
  corr_g<<<dim3(3, 10, 4), 256, 0, stream>>>(f1n2, f2n2, d1p[2], d2p[2], dw, out + 10368000, 40, 40);
  corr_g<<<dim3(2,  5, 4), 256, 0, stream>>>(f1n3, f2n3, d1p[3], d2p[3], dw, out + 10886400, 20, 20);
}

// Round 22
// 238.898 us; speedup vs baseline: 1.0566x; 1.0566x over previous
//
#include <hip/hip_runtime.h>
#include <hip/hip_bf16.h>

// r22 = r19 (best, 242.1us) + prep kernel merging {zero_halo<160>, zero_halo<80>,
// pool_d 160->80, depth 160->40 direct mean-of-means} into one first dispatch
// (12 -> 10 launches). norm reverted per r20 pre-commitment: 7 variants proved
// a ~107us structural floor (duration invariant to occupancy/ILP/DS/L3-residency).

#define B_ 4
#define C_ 256
#define ND_ 81

typedef float  f32x4 __attribute__((ext_vector_type(4)));
typedef float  f32x2 __attribute__((ext_vector_type(2)));
typedef unsigned int u32x4 __attribute__((ext_vector_type(4)));
typedef __bf16 bf16x8 __attribute__((ext_vector_type(8)));
typedef unsigned short u16x4 __attribute__((ext_vector_type(4)));

__device__ __forceinline__ unsigned short f2bf(float f) {
  unsigned int u = __builtin_bit_cast(unsigned int, f);
  u += 0x7FFFu + ((u >> 16) & 1u);   // RNE
  return (unsigned short)(u >> 16);
}

__device__ __forceinline__ void gload16(const void* g, void* l) {
  __builtin_amdgcn_global_load_lds(
      (const __attribute__((address_space(1))) unsigned int*)g,
      (__attribute__((address_space(3))) unsigned int*)l, 16, 0, 0);
}

__device__ __forceinline__ float pool2x2(const float* p0, int Wi) {
  f32x2 a = *(const f32x2*)p0;
  f32x2 c = *(const f32x2*)(p0 + Wi);
  return 0.25f * (a.x + a.y + c.x + c.y);
}

// ------- prep: halo zeroing (f2n0,f2n1) + depth pools (160->80, 160->40) -------
// All four jobs are independent; halos are disjoint from norm's interior writes.
__global__ __launch_bounds__(256) void prep(
    unsigned short* __restrict__ f2n0, unsigned short* __restrict__ f2n1,
    const float* __restrict__ dp1, const float* __restrict__ dp2,
    float* __restrict__ d1p1, float* __restrict__ d2p1,
    float* __restrict__ d1p2, float* __restrict__ d2p2) {
  constexpr long UN0 = (long)B_ * 168 * 168 * 32;   // f2n0 halo units (16B)
  constexpr long UN1 = (long)B_ * 88 * 88 * 32;     // f2n1 halo units
  constexpr long ND1 = 2L * B_ * 6400;              // depth 80x80 outputs
  constexpr long ND2 = 2L * B_ * 1600;              // depth 40x40 outputs
  long i = (long)blockIdx.x * 256 + threadIdx.x;
  if (i < UN0) {
    constexpr int Wp = 168;
    long px = i >> 5;
    long pp = px % ((long)Wp * Wp);
    int y = (int)(pp / Wp), x = (int)(pp - (long)(pp / Wp) * Wp);
    if (y < 4 || y >= Wp - 4 || x < 4 || x >= Wp - 4) {
      u16x4 z4 = {0, 0, 0, 0};
      *(u16x4*)&f2n0[i * 8] = z4;
    }
    return;
  }
  i -= UN0;
  if (i < UN1) {
    constexpr int Wp = 88;
    long px = i >> 5;
    long pp = px % ((long)Wp * Wp);
    int y = (int)(pp / Wp), x = (int)(pp - (long)(pp / Wp) * Wp);
    if (y < 4 || y >= Wp - 4 || x < 4 || x >= Wp - 4) {
      u16x4 z4 = {0, 0, 0, 0};
      *(u16x4*)&f2n1[i * 8] = z4;
    }
    return;
  }
  i -= UN1;
  if (i < ND1) {   // 2x2 pool dp -> d1p1/d2p1 (80x80)
    const float* src = (i < B_ * 6400) ? dp1 : dp2;
    float* dst = (i < B_ * 6400) ? d1p1 : d2p1;
    int r = (int)((i < B_ * 6400) ? i : i - B_ * 6400);
    int pl = r / 6400, pix = r - pl * 6400;
    int yo = pix / 80, xo = pix - yo * 80;
    dst[r] = pool2x2(src + ((long)pl * 160 + 2 * yo) * 160 + 2 * xo, 160);
    return;
  }
  i -= ND1;
  if (i < ND2) {   // 4x4 pool dp -> d1p2/d2p2 (40x40), mean-of-means order
    const float* src = (i < B_ * 1600) ? dp1 : dp2;
    float* dst = (i < B_ * 1600) ? d1p2 : d2p2;
    int r = (int)((i < B_ * 1600) ? i : i - B_ * 1600);
    int pl = r / 1600, pix = r - pl * 1600;
    int yo = pix / 40, xo = pix - yo * 40;
    const float* base = src + ((long)pl * 160 + 4 * yo) * 160 + 4 * xo;
    float q00 = pool2x2(base, 160);
    float q01 = pool2x2(base + 2, 160);
    float q10 = pool2x2(base + 2 * 160, 160);
    float q11 = pool2x2(base + 2 * 160 + 2, 160);
    dst[r] = 0.25f * ((q00 + q01) + (q10 + q11));
  }
}

// ------- fused: normalize+transpose (padded dst2) + 2x2 pool, lane-local -------
// r19-proven: 2x32 tile, 256 threads, FULLX guard-folding.
template<int W>
__global__ __launch_bounds__(256) void norm_pool(
    const float* __restrict__ src1, const float* __restrict__ src2,
    unsigned short* __restrict__ dst1, unsigned short* __restrict__ dst2,
    float* __restrict__ pool1, float* __restrict__ pool2) {
  constexpr int HW = W * W, Wp = W + 8, W1 = W / 2, HW1 = W1 * W1;
  constexpr bool FULLX = (W % 32 == 0);
  __shared__ unsigned short raw[64 * 260];
  __shared__ float ssl[256][4];
  __shared__ float inv[64];
  int tid = threadIdx.x;
  int lane = tid & 63, w = tid >> 6;
  int cg = lane >> 4, pq = lane & 15;
  int x0 = blockIdx.x * 32, y0 = blockIdx.y * 2;
  int z = blockIdx.z, b = z >> 1;
  bool pad = (z & 1) != 0;
  const float* src = pad ? src2 : src1;
  unsigned short* dst = pad ? dst2 : dst1;
  float* pooled = pad ? pool2 : pool1;
  bool okc = FULLX || ((x0 + 2 * pq) < W);
  const float* base0 = src + (long)b * C_ * HW + (long)y0 * W + x0 + 2 * pq;
  long pbase = (long)b * C_ * HW1 + (long)(y0 >> 1) * W1 + (x0 >> 1) + pq;
  int p00 = 2 * pq, p10 = 32 + 2 * pq;

  float ss0 = 0.f, ss1 = 0.f, ss2 = 0.f, ss3 = 0.f;
  f32x2 va[4][2];
  for (int sb = 0; sb < 4; ++sb) {
    int c0 = w * 64 + sb * 16 + cg * 4;
#pragma unroll
    for (int j = 0; j < 4; ++j) {
      f32x2 z2 = {0.f, 0.f};
      va[j][0] = z2; va[j][1] = z2;
      if (okc) {
        va[j][0] = *(const f32x2*)(base0 + (long)(c0 + j) * HW);
        va[j][1] = *(const f32x2*)(base0 + (long)(c0 + j) * HW + W);
      }
    }
    u16x4 pk00, pk01, pk10, pk11;
#pragma unroll
    for (int j = 0; j < 4; ++j) {
      float v00 = va[j][0].x, v01 = va[j][0].y;
      float v10 = va[j][1].x, v11 = va[j][1].y;
      ss0 += v00 * v00; ss1 += v01 * v01;
      ss2 += v10 * v10; ss3 += v11 * v11;
      pk00[j] = f2bf(v00); pk01[j] = f2bf(v01);
      pk10[j] = f2bf(v10); pk11[j] = f2bf(v11);
      if (okc) pooled[pbase + (long)(c0 + j) * HW1] = 0.25f * ((v00 + v01) + (v10 + v11));
    }
    *(u16x4*)&raw[p00 * 260 + c0]       = pk00;   // ds_write_b64
    *(u16x4*)&raw[(p00 + 1) * 260 + c0] = pk01;
    *(u16x4*)&raw[p10 * 260 + c0]       = pk10;
    *(u16x4*)&raw[(p10 + 1) * 260 + c0] = pk11;
  }
  ssl[tid][0] = ss0; ssl[tid][1] = ss1; ssl[tid][2] = ss2; ssl[tid][3] = ss3;
  __syncthreads();
  if (tid < 64) {
    int r = tid >> 5, col = tid & 31;
    int pq2 = col >> 1, j = r * 2 + (col & 1);
    float s = 0.f;
#pragma unroll
    for (int ww = 0; ww < 4; ++ww)
#pragma unroll
      for (int g = 0; g < 4; ++g)
        s += ssl[ww * 64 + g * 16 + pq2][j];
    inv[tid] = 1.f / fmaxf(sqrtf(s), 1e-12f);
  }
  __syncthreads();

  int c4 = lane * 4;
  for (int p = w; p < 64; p += 4) {
    int y = y0 + (p >> 5), x = x0 + (p & 31);
    if (FULLX || x < W) {
      long off;
      if (pad) off = (((long)b * Wp + (y + 4)) * Wp + (x + 4)) * C_ + c4;
      else     off = ((long)b * HW + (long)y * W + x) * C_ + c4;
      u16x4 r = *(const u16x4*)&raw[p * 260 + c4];
      float sc = inv[p];
      u16x4 o;
#pragma unroll
      for (int j = 0; j < 4; ++j) {
        float v = __builtin_bit_cast(float, ((unsigned int)r[j]) << 16) * sc;
        o[j] = f2bf(v);
      }
      *(u16x4*)&dst[off] = o;
    }
  }
}

// ------- 2x2 average pooling (fmaps+depth), level 2->3 (r10-proven) -------
template<int Ho, int Wo>
__global__ __launch_bounds__(256) void pool16(
    const float* __restrict__ f1i, const float* __restrict__ f2i,
    const float* __restrict__ d1i, const float* __restrict__ d2i,
    float* __restrict__ f1o, float* __restrict__ f2o,
    float* __restrict__ d1o, float* __restrict__ d2o) {
  constexpr long HWo = (long)Ho * Wo;
  constexpr long G4F = (long)B_ * C_ * HWo / 4;
  constexpr long G4D = (long)B_ * HWo / 4;
  constexpr long N   = 2 * G4F + 2 * G4D;
  constexpr long TT  = N / 4;
  long t = (long)blockIdx.x * blockDim.x + threadIdx.x;
  if (t >= TT) return;
  f32x4 va[4][4];
  float* dsts[4];
  long   gs[4];
#pragma unroll
  for (int j = 0; j < 4; ++j) {
    long g = t + (long)j * TT;
    const float* src; float* dst;
    if      (g < G4F)           { src = f1i; dst = f1o; }
    else if (g < 2*G4F)         { src = f2i; dst = f2o; g -= G4F; }
    else if (g < 2*G4F + G4D)   { src = d1i; dst = d1o; g -= 2*G4F; }
    else                        { src = d2i; dst = d2o; g -= 2*G4F + G4D; }
    constexpr long GP = HWo / 4;
    long plane = g / GP;
    long gp    = g - plane * GP;
    int  yo    = (int)(gp / (Wo / 4));
    int  xg    = (int)(gp - (long)yo * (Wo / 4));
    constexpr int Wi = 2 * Wo;
    const float* p0 = src + (plane * (2 * Ho) + 2 * yo) * (long)Wi + 8 * xg;
    va[j][0] = *(const f32x4*)p0;
    va[j][1] = *(const f32x4*)(p0 + 4);
    va[j][2] = *(const f32x4*)(p0 + Wi);
    va[j][3] = *(const f32x4*)(p0 + Wi + 4);
    dsts[j] = dst;
    gs[j]   = g;
  }
#pragma unroll
  for (int j = 0; j < 4; ++j) {
    f32x4 o;
    o.x = 0.25f * (va[j][0].x + va[j][0].y + va[j][2].x + va[j][2].y);
    o.y = 0.25f * (va[j][0].z + va[j][0].w + va[j][2].z + va[j][2].w);
    o.z = 0.25f * (va[j][1].x + va[j][1].y + va[j][3].x + va[j][3].y);
    o.w = 0.25f * (va[j][1].z + va[j][1].w + va[j][3].z + va[j][3].w);
    *(f32x4*)(dsts[j] + 4 * gs[j]) = o;
  }
}

// ------- r4-proven: normalize + transpose, both compact (L2/L3 path) -------
__global__ __launch_bounds__(256) void norm_tp_c(
    const float* __restrict__ src1, const float* __restrict__ src2,
    unsigned short* __restrict__ dst1, unsigned short* __restrict__ dst2, int HW_) {
  __shared__ unsigned short raw[64 * 260];
  __shared__ float ssp[4][64];
  __shared__ float inv[64];
  int tid = threadIdx.x;
  int lane = tid & 63, w = tid >> 6;
  long HW = HW_;
  long pix0 = (long)blockIdx.x * 64;
  int z = blockIdx.z, b = z >> 1;
  const float* src = (z & 1) ? src2 : src1;
  unsigned short* dst = (z & 1) ? dst2 : dst1;
  bool ok = (pix0 + lane) < HW;
  const float* base = src + (long)b * C_ * HW + pix0 + lane;

  float ss = 0.f;
  float vv[16];
  for (int cb = 0; cb < 64; cb += 16) {
    int c0 = w * 64 + cb;
#pragma unroll
    for (int j = 0; j < 16; ++j)
      vv[j] = ok ? base[(long)(c0 + j) * HW] : 0.f;
#pragma unroll
    for (int g = 0; g < 4; ++g) {
      u16x4 pk;
#pragma unroll
      for (int j = 0; j < 4; ++j) {
        float v = vv[g * 4 + j];
        ss += v * v;
        pk[j] = f2bf(v);
      }
      *(u16x4*)&raw[lane * 260 + c0 + g * 4] = pk;
    }
  }
  ssp[w][lane] = ss;
  __syncthreads();
  if (tid < 64) {
    float s = ssp[0][tid] + ssp[1][tid] + ssp[2][tid] + ssp[3][tid];
    inv[tid] = 1.f / fmaxf(sqrtf(s), 1e-12f);
  }
  __syncthreads();
  int c4 = lane * 4;
  unsigned short* dbase = dst + ((long)b * HW + pix0) * C_;
  for (int p = w; p < 64; p += 4) {
    if (pix0 + p < HW) {
      u16x4 r = *(const u16x4*)&raw[p * 260 + c4];
      float sc = inv[p];
      u16x4 o;
#pragma unroll
      for (int j = 0; j < 4; ++j) {
        float v = __builtin_bit_cast(float, ((unsigned int)r[j]) << 16) * sc;
        o[j] = f2bf(v);
      }
      *(u16x4*)&dbase[(long)p * C_ + c4] = o;
    }
  }
}

// ---------------- corr2: LDS-staged, K-chunked, XCD-swizzled (L0/L1) ----------------
template<int W>
__global__ __launch_bounds__(256, 3) void corr2(
    const unsigned short* __restrict__ f1n, const unsigned short* __restrict__ f2pd,
    const float* __restrict__ d1, const float* __restrict__ d2,
    const float* __restrict__ dwp, float* __restrict__ out) {
  constexpr int H = W, Wp = W + 8, Hp = H + 8;
  constexpr int GX = (W + 15) / 16, GY = H / 4;
  constexpr int NB = GX * GY * B_;
  constexpr int CPX = NB / 8;
  constexpr int BUFB = 18944;
  __shared__ char smem[2 * BUFB];
  unsigned short* sb = (unsigned short*)smem;

  int tid = threadIdx.x;
  int lane = tid & 63, wv = tid >> 6;
  int n16 = lane & 15, hi = lane >> 4;

  int f = blockIdx.x;
  int nf = (f & 7) * CPX + (f >> 3);
  int j = nf % GY;
  int rest = nf / GY;
  int i = rest % GX;
  int b = rest / GX;
  int x0 = i * 16, y0 = j * 4, y = y0 + wv;
  long HW = (long)W * H;

  int xm = x0 + n16;
  bool aok = xm < W;
  const unsigned short* abase = f1n + ((long)b * HW + (long)y * W + xm) * C_ + hi * 8;
  bf16x8 afr[8];
#pragma unroll
  for (int kc = 0; kc < 8; ++kc) {
    u32x4 rr = {0u, 0u, 0u, 0u};
    if (aok) rr = *(const u32x4*)(abase + kc * 32);
    afr[kc] = __builtin_bit_cast(bf16x8, rr);
  }

  const char* gbase = (const char*)f2pd;
  long gb[5];
#pragma unroll
  for (int it = 0; it < 5; ++it) {
    int u = tid + it * 256;
    int u2 = (u < 1152) ? u : 0;
    int sl = (u2 & ~7) | ((u2 & 7) ^ ((u2 >> 3) & 7));
    int px = sl >> 2, s = sl & 3;
    int row = px / 24, col = px - row * 24;
    int gx = x0 + col; if (gx > Wp - 1) gx = Wp - 1;
    int gy = y0 + row;
    gb[it] = (((long)b * Hp + gy) * Wp + gx) * 512 + s * 16;
  }

  f32x4 acc[9][2];
#pragma unroll
  for (int dy = 0; dy < 9; ++dy)
#pragma unroll
    for (int nt = 0; nt < 2; ++nt)
      acc[dy][nt] = f32x4{0.f, 0.f, 0.f, 0.f};

#pragma unroll
  for (int it = 0; it < 5; ++it)
    if (tid + it * 256 < 1152)
      gload16(gbase + gb[it], smem + (tid + it * 256) * 16);
  __syncthreads();

#pragma unroll
  for (int kc = 0; kc < 8; ++kc) {
    int cur = kc & 1;
    if (kc < 7) {
      char* dstb = smem + (cur ^ 1) * BUFB;
#pragma unroll
      for (int it = 0; it < 5; ++it)
        if (tid + it * 256 < 1152)
          gload16(gbase + gb[it] + (long)(kc + 1) * 64, dstb + (tid + it * 256) * 16);
    }
    const unsigned short* bufc = sb + cur * (BUFB / 2);
#pragma unroll
    for (int dy = 0; dy < 9; ++dy) {
      int rbase = (wv + dy) * 96;
#pragma unroll
      for (int nt = 0; nt < 2; ++nt) {
        int sl = rbase + (nt * 16 + n16) * 4 + hi;
        int ph = (sl & ~7) | ((sl & 7) ^ ((sl >> 3) & 7));
        bf16x8 bfr = *(const bf16x8*)(bufc + ph * 8);
        acc[dy][nt] = __builtin_amdgcn_mfma_f32_16x16x32_bf16(afr[kc], bfr, acc[dy][nt], 0, 0, 0);
      }
    }
    __syncthreads();
  }

  float* lds_o = (float*)smem;
  float* dt = (float*)(smem + 64 * ND_ * 4);
#pragma unroll
  for (int dy = 0; dy < 9; ++dy)
#pragma unroll
    for (int nt = 0; nt < 2; ++nt)
#pragma unroll
      for (int r = 0; r < 4; ++r) {
        int m = hi * 4 + r;
        int dx = nt * 16 + n16 - m - 4;
        if (dx >= -4 && dx <= 4) {
          int d = (8 - dy) * 9 + (4 - dx);
          lds_o[(wv * 16 + m) * ND_ + d] = acc[dy][nt][r];
        }
      }
  if (tid < 64) {
    int ty = tid >> 4, tx = tid & 15;
    int xq = x0 + tx, yq = y0 + ty;
    float v = 0.f;
    if (xq < W) {
      long pidx = (long)b * HW + (long)yq * W + xq;
      v = dwp[0] * expf(-fabsf(d1[pidx] - d2[pidx]));
    }
    dt[tid] = v;
  }
  __syncthreads();
  long obase = (long)b * ND_ * HW;
  for (int it = 0; it < 21; ++it) {
    int flat = it * 256 + tid;
    if (flat < 64 * ND_) {
      int d = flat >> 6;
      int p = flat & 63;
      int xq = x0 + (p & 15);
      if (xq < W)
        out[obase + (long)d * HW + (long)(y0 + (p >> 4)) * W + xq] = lds_o[p * ND_ + d] + dt[p];
    }
  }
}

// ---------------- r4-proven corr (global-B, compact buffers) — L2/L3 ----------------
__global__ __launch_bounds__(256, 2) void corr_g(
    const unsigned short* __restrict__ f1n, const unsigned short* __restrict__ f2n,
    const float* __restrict__ d1, const float* __restrict__ d2,
    const float* __restrict__ dwp, float* __restrict__ out, int H, int W) {
  __shared__ float lds_o[64 * ND_];
  __shared__ float dt[64];
  int tid = threadIdx.x;
  int lane = tid & 63, wv = tid >> 6;
  int x0 = blockIdx.x * 16, y0 = blockIdx.y * 4, b = blockIdx.z;
  int y = y0 + wv;
  int n16 = lane & 15, hi = lane >> 4;
  long HW = (long)H * W;

  int xm = x0 + n16;
  bool aok = xm < W;
  const unsigned short* abase = f1n + ((long)b * HW + (long)y * W + xm) * C_ + hi * 8;
  bf16x8 afr[8];
#pragma unroll
  for (int ch = 0; ch < 8; ++ch) {
    u32x4 rr = {0u, 0u, 0u, 0u};
    if (aok) rr = *(const u32x4*)(abase + ch * 32);
    afr[ch] = __builtin_bit_cast(bf16x8, rr);
  }

  f32x4 acc[9][2];
#pragma unroll
  for (int dy = 0; dy < 9; ++dy)
#pragma unroll
    for (int nt = 0; nt < 2; ++nt)
      acc[dy][nt] = f32x4{0.f, 0.f, 0.f, 0.f};

#pragma unroll
  for (int dy = 0; dy < 9; ++dy) {
    int yy = y + dy - 4;
    if (yy >= 0 && yy < H) {
      const unsigned short* brow = f2n + ((long)b * HW + (long)yy * W) * C_;
#pragma unroll
      for (int nt = 0; nt < 2; ++nt) {
        int wx = x0 - 4 + nt * 16 + n16;
        bool bok = (wx >= 0) && (wx < W);
        const unsigned short* bbase = brow + (long)wx * C_ + hi * 8;
        bf16x8 bfr[8];
#pragma unroll
        for (int ch = 0; ch < 8; ++ch) {
          u32x4 rr = {0u, 0u, 0u, 0u};
          if (bok) rr = *(const u32x4*)(bbase + ch * 32);
          bfr[ch] = __builtin_bit_cast(bf16x8, rr);
        }
#pragma unroll
        for (int ch = 0; ch < 8; ++ch)
          acc[dy][nt] = __builtin_amdgcn_mfma_f32_16x16x32_bf16(afr[ch], bfr[ch], acc[dy][nt], 0, 0, 0);
      }
    }
  }

#pragma unroll
  for (int dy = 0; dy < 9; ++dy)
#pragma unroll
    for (int nt = 0; nt < 2; ++nt)
#pragma unroll
      for (int r = 0; r < 4; ++r) {
        int m = hi * 4 + r;
        int dx = nt * 16 + n16 - m - 4;
        if (dx >= -4 && dx <= 4) {
          int d = (8 - dy) * 9 + (4 - dx);
          lds_o[(wv * 16 + m) * ND_ + d] = acc[dy][nt][r];
        }
      }
  if (tid < 64) {
    int ty = tid >> 4, tx = tid & 15;
    int xq = x0 + tx, yq = y0 + ty;
    float v = 0.f;
    if (xq < W) {
      long pidx = (long)b * HW + (long)yq * W + xq;
      v = dwp[0] * expf(-fabsf(d1[pidx] - d2[pidx]));
    }
    dt[tid] = v;
  }
  __syncthreads();
  long obase = (long)b * ND_ * HW;
  for (int it = 0; it < 21; ++it) {
    int flat = it * 256 + tid;
    if (flat < 64 * ND_) {
      int d = flat >> 6;
      int p = flat & 63;
      int xq = x0 + (p & 15);
      if (xq < W)
        out[obase + (long)d * HW + (long)(y0 + (p >> 4)) * W + xq] = lds_o[p * ND_ + d] + dt[p];
    }
  }
}

// ---------------------------------------------------------------------------
extern "C" void kernel_launch(void* const* d_in, const int* in_sizes, int n_in,
                              void* d_out, int out_size, void* d_ws, size_t ws_size,
                              hipStream_t stream) {
  const float* f1  = (const float*)d_in[0];
  const float* f2  = (const float*)d_in[1];
  const float* dp1 = (const float*)d_in[2];
  const float* dp2 = (const float*)d_in[3];
  const float* dw  = (const float*)d_in[4];
  float* out = (float*)d_out;

  char* ws = (char*)d_ws;
  size_t off = 0;
  auto alloc = [&](size_t bytes) -> void* {
    void* p = ws + off;
    off = (off + bytes + 255) & ~(size_t)255;
    return p;
  };
  static const long HWs[4] = {25600, 6400, 1600, 400};
  float* f1p[4]; float* f2p[4]; float* d1p[4]; float* d2p[4];
  for (int l = 1; l <= 3; ++l) f1p[l] = (float*)alloc((size_t)B_ * C_ * HWs[l] * 4);
  for (int l = 1; l <= 3; ++l) f2p[l] = (float*)alloc((size_t)B_ * C_ * HWs[l] * 4);
  for (int l = 1; l <= 3; ++l) d1p[l] = (float*)alloc((size_t)B_ * HWs[l] * 4);
  for (int l = 1; l <= 3; ++l) d2p[l] = (float*)alloc((size_t)B_ * HWs[l] * 4);
  unsigned short* f1n0 = (unsigned short*)alloc((size_t)B_ * 25600 * C_ * 2);
  unsigned short* f1n1 = (unsigned short*)alloc((size_t)B_ * 6400 * C_ * 2);
  unsigned short* f2n0 = (unsigned short*)alloc((size_t)B_ * 168 * 168 * C_ * 2);
  unsigned short* f2n1 = (unsigned short*)alloc((size_t)B_ * 88 * 88 * C_ * 2);
  unsigned short* f1n2 = (unsigned short*)alloc((size_t)B_ * 1600 * C_ * 2);
  unsigned short* f2n2 = (unsigned short*)alloc((size_t)B_ * 1600 * C_ * 2);
  unsigned short* f1n3 = (unsigned short*)alloc((size_t)B_ * 400 * C_ * 2);
  unsigned short* f2n3 = (unsigned short*)alloc((size_t)B_ * 400 * C_ * 2);
  if (off > ws_size) return;

  // 1) prep: halos + depth pools (80x80 and 40x40), one dispatch
  prep<<<dim3(18234), 256, 0, stream>>>(f2n0, f2n1, dp1, dp2,
                                        d1p[1], d2p[1], d1p[2], d2p[2]);

  // 2) fused L0/L1 normalize+pool (fmaps)
  norm_pool<160><<<dim3(5, 80, 8), 256, 0, stream>>>(f1, f2, f1n0, f2n0, f1p[1], f2p[1]);
  norm_pool<80><<<dim3(3, 40, 8), 256, 0, stream>>>(f1p[1], f2p[1], f1n1, f2n1, f1p[2], f2p[2]);
  pool16<20, 20><<<dim3(201), 256, 0, stream>>>(
      f1p[2], f2p[2], d1p[2], d2p[2], f1p[3], f2p[3], d1p[3], d2p[3]);

  // 3) staged corr L0/L1
  corr2<160><<<dim3(1600), 256, 0, stream>>>(f1n0, f2n0, dp1,    dp2,    dw, out);
  corr2< 80><<<dim3( 400), 256, 0, stream>>>(f1n1, f2n1, d1p[1], d2p[1], dw, out + 8294400);

  // 4) L2/L3: r4-proven compact path (distinct buffers)
  norm_tp_c<<<dim3(25, 1, 8), 256, 0, stream>>>(f1p[2], f2p[2], f1n2, f2n2, 1600);
  norm_tp_c<<<dim3( 7, 1, 8), 256, 0, stream>>>(f1p[3], f2p[3], f1n3, f2n3, 400);
  corr_g<<<dim3(3, 10, 4), 256, 0, stream>>>(f1n2, f2n2, d1p[2], d2p[2], dw, out + 10368000, 40, 40);
  corr_g<<<dim3(2,  5, 4), 256, 0, stream>>>(f1n3, f2n3, d1p[3], d2p[3], dw, out + 10886400, 20, 20);
}